// Round 1
// baseline (12214.105 us; speedup 1.0000x reference)
//
#include <hip/hip_runtime.h>
#include <math.h>

#define T_STEPS 12
#define NNODE 1024
#define BBATCH 64
#define HHID 64
#define DDIM 16
#define CCH 65                 // C_IN + H
#define BC (BBATCH*CCH)        // 4160
#define XGROWS 196             // 3*65 + 1 (bias row)
#define XGLD 65                // padded stride for xg rows

// ---------------- embed + double layernorm ----------------
__global__ __launch_bounds__(256) void k_embed_ln(
    const float* __restrict__ node_emb, const float* __restrict__ te_t,
    const float* __restrict__ gg, const float* __restrict__ gb,
    const float* __restrict__ ug, const float* __restrict__ ub,
    float* __restrict__ neg, float* __restrict__ neu)
{
  int n = blockIdx.x * blockDim.x + threadIdx.x;
  if (n >= NNODE) return;
  float e[DDIM];
  float mu = 0.f;
#pragma unroll
  for (int d = 0; d < DDIM; ++d) { e[d] = node_emb[n*DDIM+d] + te_t[d]; mu += e[d]; }
  mu *= (1.0f/DDIM);
  float var = 0.f;
#pragma unroll
  for (int d = 0; d < DDIM; ++d) { float z = e[d]-mu; var += z*z; }
  var *= (1.0f/DDIM);
  float rstd = rsqrtf(var + 1e-12f);
#pragma unroll
  for (int d = 0; d < DDIM; ++d) {
    float z = (e[d]-mu)*rstd;
    neg[n*DDIM+d] = z*gg[d] + gb[d];
    neu[n*DDIM+d] = z*ug[d] + ub[d];
  }
}

// ---------------- adjacency: S = softmax(ne @ ne^T, axis=1) ----------------
__global__ __launch_bounds__(256) void k_adjacency(
    const float* __restrict__ neg, const float* __restrict__ neu,
    float* __restrict__ Sg, float* __restrict__ Su)
{
  const float* ne = blockIdx.y ? neu : neg;
  float* S = blockIdx.y ? Su : Sg;
  int n = blockIdx.x;
  int tid = threadIdx.x;
  const float4* rp = (const float4*)(ne + n*DDIM);
  float4 r0 = rp[0], r1 = rp[1], r2 = rp[2], r3 = rp[3];
  float v[4]; float mx = -3.4e38f;
#pragma unroll
  for (int j = 0; j < 4; ++j) {
    int m = tid + j*256;
    const float4* p = (const float4*)(ne + m*DDIM);
    float4 q0 = p[0], q1 = p[1], q2 = p[2], q3 = p[3];
    float dot = r0.x*q0.x + r0.y*q0.y + r0.z*q0.z + r0.w*q0.w
              + r1.x*q1.x + r1.y*q1.y + r1.z*q1.z + r1.w*q1.w
              + r2.x*q2.x + r2.y*q2.y + r2.z*q2.z + r2.w*q2.w
              + r3.x*q3.x + r3.y*q3.y + r3.z*q3.z + r3.w*q3.w;
    v[j] = dot; mx = fmaxf(mx, dot);
  }
  __shared__ float red[256];
  red[tid] = mx; __syncthreads();
#pragma unroll
  for (int s = 128; s > 0; s >>= 1) {
    if (tid < s) red[tid] = fmaxf(red[tid], red[tid+s]);
    __syncthreads();
  }
  mx = red[0]; __syncthreads();
  float sum = 0.f;
#pragma unroll
  for (int j = 0; j < 4; ++j) { v[j] = expf(v[j] - mx); sum += v[j]; }
  red[tid] = sum; __syncthreads();
#pragma unroll
  for (int s = 128; s > 0; s >>= 1) {
    if (tid < s) red[tid] += red[tid+s];
    __syncthreads();
  }
  float inv = 1.0f / red[0];
#pragma unroll
  for (int j = 0; j < 4; ++j) S[n*NNODE + tid + j*256] = v[j]*inv;
}

// ---------------- pack X[m][b*65+c] = {x_t, state} ----------------
__global__ __launch_bounds__(256) void k_pack(
    const float* __restrict__ xt,    // x + t*NNODE ; element b*(T*N) + m
    const float* __restrict__ state, // [N][B][H]
    float* __restrict__ X)           // [N][BC]
{
  int m = blockIdx.x;
  for (int idx = threadIdx.x; idx < BC; idx += 256) {
    int b = idx / CCH, c = idx % CCH;
    float v = (c == 0) ? xt[b*(T_STEPS*NNODE) + m] : state[(m*BBATCH + b)*HHID + (c-1)];
    X[m*BC + idx] = v;
  }
}

// ---------------- fp32 GEMM: C[1024][4160] = A[1024][1024] * B[1024][4160] ----
#define GBM 128
#define GBN 64
#define GBK 16
__global__ __launch_bounds__(256) void k_gemm(
    const float* __restrict__ A, const float* __restrict__ B, float* __restrict__ C)
{
  __shared__ float As[GBK][GBM];
  __shared__ float Bs[GBK][GBN];
  const int K = NNODE, LDB = BC;
  int n0 = blockIdx.x * GBN;
  int m0 = blockIdx.y * GBM;
  int tid = threadIdx.x;
  int tx = tid & 15;   // col group: cols tx*4..+3
  int ty = tid >> 4;   // row group: rows ty*8..+7
  float acc[8][4] = {};
  for (int k0 = 0; k0 < K; k0 += GBK) {
#pragma unroll
    for (int l = 0; l < 2; ++l) {
      int i = tid + l*256;
      int row = i >> 2, c4 = (i & 3)*4;
      float4 v = *(const float4*)(A + (m0+row)*K + k0 + c4);
      As[c4+0][row] = v.x; As[c4+1][row] = v.y; As[c4+2][row] = v.z; As[c4+3][row] = v.w;
    }
    {
      int row = tid >> 4, c4 = (tid & 15)*4;
      *(float4*)(&Bs[row][c4]) = *(const float4*)(B + (k0+row)*LDB + n0 + c4);
    }
    __syncthreads();
#pragma unroll
    for (int kk = 0; kk < GBK; ++kk) {
      float a[8], b[4];
#pragma unroll
      for (int i = 0; i < 8; ++i) a[i] = As[kk][ty*8+i];
#pragma unroll
      for (int j = 0; j < 4; ++j) b[j] = Bs[kk][tx*4+j];
#pragma unroll
      for (int i = 0; i < 8; ++i)
#pragma unroll
        for (int j = 0; j < 4; ++j) acc[i][j] += a[i]*b[j];
    }
    __syncthreads();
  }
#pragma unroll
  for (int i = 0; i < 8; ++i) {
    int row = m0 + ty*8 + i;
    float4 v = { acc[i][0], acc[i][1], acc[i][2], acc[i][3] };
    *(float4*)(C + row*LDB + n0 + tx*4) = v;
  }
}

// ---------------- gate GCN output: sigmoid -> z (writes z*state into X), r ----
__global__ __launch_bounds__(256) void k_gate_out(
    float* __restrict__ X,            // [N][BC] rows read, cols 1..64 rewritten with z*state
    const float* __restrict__ Y1,
    const float* __restrict__ Y2,
    const float* __restrict__ neg,    // [N][16]
    const float* __restrict__ gW,     // [16][3][65][128]
    const float* __restrict__ gb,     // [16][128]
    float* __restrict__ rbuf,         // [N][B][64]
    const float* __restrict__ state)  // [N][B][64]
{
  int n = blockIdx.x;
  __shared__ float xg[XGROWS*XGLD];   // [196][65]
  __shared__ float wn[XGROWS*32];     // [196][32]
  __shared__ float sne[DDIM];
  int tid = threadIdx.x;
  if (tid < DDIM) sne[tid] = neg[n*DDIM + tid];
  const float* Xr = X + n*BC;
  const float* Y1r = Y1 + n*BC;
  const float* Y2r = Y2 + n*BC;
  for (int idx = tid; idx < BC; idx += 256) {
    int b = idx / CCH, c = idx % CCH;
    float x0 = Xr[idx], a1 = Y1r[idx], a2 = Y2r[idx];
    xg[c*XGLD + b]        = x0;
    xg[(65+c)*XGLD + b]   = a1;
    xg[(130+c)*XGLD + b]  = 2.0f*a2 - x0;
  }
  if (tid < BBATCH) xg[195*XGLD + tid] = 1.0f;
  __syncthreads();
  int b  = tid & 63;
  int og = tid >> 6;   // 0..3, owns 8 output cols
  for (int chunk = 0; chunk < 4; ++chunk) {
    int o0 = chunk*32;
    for (int idx = tid; idx < XGROWS*32; idx += 256) {
      int ki = idx >> 5, oc = idx & 31;
      float w = 0.f;
      if (ki < 195) {
        int k = ki / 65, i = ki % 65;
        const float* wp = gW + (k*65 + i)*128 + (o0 + oc);
#pragma unroll
        for (int d = 0; d < DDIM; ++d) w += sne[d] * wp[d*24960];
      } else {
#pragma unroll
        for (int d = 0; d < DDIM; ++d) w += sne[d] * gb[d*128 + o0 + oc];
      }
      wn[idx] = w;
    }
    __syncthreads();
    float acc[8] = {};
#pragma unroll 4
    for (int ki = 0; ki < XGROWS; ++ki) {
      float xv = xg[ki*XGLD + b];
#pragma unroll
      for (int j = 0; j < 8; ++j) acc[j] += xv * wn[ki*32 + og*8 + j];
    }
#pragma unroll
    for (int j = 0; j < 8; ++j) {
      int o = o0 + og*8 + j;
      float s = 1.0f / (1.0f + expf(-acc[j]));
      if (o < HHID) {
        X[n*BC + b*CCH + 1 + o] = s * state[(n*BBATCH + b)*HHID + o];   // z*state
      } else {
        rbuf[(n*BBATCH + b)*HHID + (o - HHID)] = s;                     // r
      }
    }
    __syncthreads();
  }
}

// ---------------- update GCN output: tanh -> h; write out + state ----------
__global__ __launch_bounds__(256) void k_update_out(
    const float* __restrict__ X,      // candidate
    const float* __restrict__ Y1,
    const float* __restrict__ Y2,
    const float* __restrict__ neu,    // [N][16]
    const float* __restrict__ uW,     // [16][3][65][64]
    const float* __restrict__ ub,     // [16][64]
    const float* __restrict__ rbuf,   // [N][B][64]
    float* __restrict__ state,        // [N][B][64]
    float* __restrict__ outT)         // out + t*N*H ; element b*(T*N*H) + n*H + o
{
  int n = blockIdx.x;
  __shared__ float xg[XGROWS*XGLD];
  __shared__ float wn[XGROWS*32];
  __shared__ float sne[DDIM];
  int tid = threadIdx.x;
  if (tid < DDIM) sne[tid] = neu[n*DDIM + tid];
  const float* Xr = X + n*BC;
  const float* Y1r = Y1 + n*BC;
  const float* Y2r = Y2 + n*BC;
  for (int idx = tid; idx < BC; idx += 256) {
    int b = idx / CCH, c = idx % CCH;
    float x0 = Xr[idx], a1 = Y1r[idx], a2 = Y2r[idx];
    xg[c*XGLD + b]        = x0;
    xg[(65+c)*XGLD + b]   = a1;
    xg[(130+c)*XGLD + b]  = 2.0f*a2 - x0;
  }
  if (tid < BBATCH) xg[195*XGLD + tid] = 1.0f;
  __syncthreads();
  int b  = tid & 63;
  int og = tid >> 6;
  for (int chunk = 0; chunk < 2; ++chunk) {
    int o0 = chunk*32;
    for (int idx = tid; idx < XGROWS*32; idx += 256) {
      int ki = idx >> 5, oc = idx & 31;
      float w = 0.f;
      if (ki < 195) {
        int k = ki / 65, i = ki % 65;
        const float* wp = uW + (k*65 + i)*64 + (o0 + oc);
#pragma unroll
        for (int d = 0; d < DDIM; ++d) w += sne[d] * wp[d*12480];
      } else {
#pragma unroll
        for (int d = 0; d < DDIM; ++d) w += sne[d] * ub[d*64 + o0 + oc];
      }
      wn[idx] = w;
    }
    __syncthreads();
    float acc[8] = {};
#pragma unroll 4
    for (int ki = 0; ki < XGROWS; ++ki) {
      float xv = xg[ki*XGLD + b];
#pragma unroll
      for (int j = 0; j < 8; ++j) acc[j] += xv * wn[ki*32 + og*8 + j];
    }
#pragma unroll
    for (int j = 0; j < 8; ++j) {
      int o = o0 + og*8 + j;
      float hc = tanhf(acc[j]);
      int si = (n*BBATCH + b)*HHID + o;
      float r = rbuf[si];
      float st = state[si];
      float h = r*st + (1.0f - r)*hc;
      state[si] = h;
      outT[b*(T_STEPS*NNODE*HHID) + n*HHID + o] = h;
    }
    __syncthreads();
  }
}

extern "C" void kernel_launch(void* const* d_in, const int* in_sizes, int n_in,
                              void* d_out, int out_size, void* d_ws, size_t ws_size,
                              hipStream_t stream) {
  const float* x          = (const float*)d_in[0];   // [64][12][1024][1]
  const float* node_emb   = (const float*)d_in[1];   // [1024][16]
  const float* time_emb   = (const float*)d_in[2];   // [12][16]
  const float* gate_W     = (const float*)d_in[3];   // [16][3][65][128]
  const float* gate_b     = (const float*)d_in[4];   // [16][128]
  const float* gate_ln_g  = (const float*)d_in[5];
  const float* gate_ln_b  = (const float*)d_in[6];
  const float* update_W   = (const float*)d_in[7];   // [16][3][65][64]
  const float* update_b   = (const float*)d_in[8];   // [16][64]
  const float* update_ln_g= (const float*)d_in[9];
  const float* update_ln_b= (const float*)d_in[10];
  float* out = (float*)d_out;                         // [64][12][1024][64]
  float* ws  = (float*)d_ws;

  float* neg   = ws;                    // 16384
  float* neu   = neg   + 16384;         // 16384
  float* Sg    = neu   + 16384;         // 1048576
  float* Su    = Sg    + 1048576;       // 1048576
  float* X     = Su    + 1048576;       // 4259840
  float* Y1    = X     + 4259840;       // 4259840
  float* Y2    = Y1    + 4259840;       // 4259840
  float* state = Y2    + 4259840;       // 4194304
  float* rbuf  = state + 4194304;       // 4194304

  hipMemsetAsync(state, 0, (size_t)4194304*sizeof(float), stream);

  for (int t = 0; t < T_STEPS; ++t) {
    k_embed_ln<<<dim3(4), 256, 0, stream>>>(node_emb, time_emb + t*DDIM,
        gate_ln_g, gate_ln_b, update_ln_g, update_ln_b, neg, neu);
    k_adjacency<<<dim3(NNODE, 2), 256, 0, stream>>>(neg, neu, Sg, Su);
    k_pack<<<dim3(NNODE), 256, 0, stream>>>(x + t*NNODE, state, X);
    k_gemm<<<dim3(BC/GBN, NNODE/GBM), 256, 0, stream>>>(Sg, X, Y1);
    k_gemm<<<dim3(BC/GBN, NNODE/GBM), 256, 0, stream>>>(Sg, Y1, Y2);
    k_gate_out<<<dim3(NNODE), 256, 0, stream>>>(X, Y1, Y2, neg, gate_W, gate_b, rbuf, state);
    k_gemm<<<dim3(BC/GBN, NNODE/GBM), 256, 0, stream>>>(Su, X, Y1);
    k_gemm<<<dim3(BC/GBN, NNODE/GBM), 256, 0, stream>>>(Su, Y1, Y2);
    k_update_out<<<dim3(NNODE), 256, 0, stream>>>(X, Y1, Y2, neu, update_W, update_b,
        rbuf, state, out + t*NNODE*HHID);
  }
}

// Round 4
// 8159.424 us; speedup vs baseline: 1.4969x; 1.4969x over previous
//
#include <hip/hip_runtime.h>
#include <math.h>

#define T_STEPS 12
#define NNODE 1024
#define BBATCH 64
#define HHID 64
#define DDIM 16
#define CCH 65                  // C_IN + H
#define BC 4160                 // 64*65 real columns
#define LDB 4224                // padded to 33*128 for 128-wide GEMM tiles
#define KI 196                  // 3*65 + bias row
#define XS_STRIDE 197
#define NCHUNK 256              // nodes per Wn chunk (4 chunks per phase)

typedef float f32x4v __attribute__((ext_vector_type(4)));
typedef float f32x2v __attribute__((ext_vector_type(2)));
typedef short short8 __attribute__((ext_vector_type(8)));
typedef unsigned short ush8 __attribute__((ext_vector_type(8)));

__device__ __forceinline__ unsigned short f2bf(float f) {
  union { float f; unsigned u; } v; v.f = f;
  unsigned r = v.u + 0x7fffu + ((v.u >> 16) & 1u);
  return (unsigned short)(r >> 16);
}
__device__ __forceinline__ float bf2f(unsigned short s) {
  union { unsigned u; float f; } v; v.u = ((unsigned)s) << 16;
  return v.f;
}

// ---------------- embed + double layernorm (fp32) ----------------
__global__ __launch_bounds__(256) void k_embed_ln(
    const float* __restrict__ node_emb, const float* __restrict__ te_t,
    const float* __restrict__ gg, const float* __restrict__ gb,
    const float* __restrict__ ug, const float* __restrict__ ub,
    float* __restrict__ neg, float* __restrict__ neu)
{
  int n = blockIdx.x * blockDim.x + threadIdx.x;
  if (n >= NNODE) return;
  float e[DDIM];
  float mu = 0.f;
#pragma unroll
  for (int d = 0; d < DDIM; ++d) { e[d] = node_emb[n*DDIM+d] + te_t[d]; mu += e[d]; }
  mu *= (1.0f/DDIM);
  float var = 0.f;
#pragma unroll
  for (int d = 0; d < DDIM; ++d) { float z = e[d]-mu; var += z*z; }
  var *= (1.0f/DDIM);
  float rstd = rsqrtf(var + 1e-12f);
#pragma unroll
  for (int d = 0; d < DDIM; ++d) {
    float z = (e[d]-mu)*rstd;
    neg[n*DDIM+d] = z*gg[d] + gb[d];
    neu[n*DDIM+d] = z*ug[d] + ub[d];
  }
}

// ------ adjacency: S = softmax(ne @ ne^T, axis=1); hi/lo bf16 split out ------
__global__ __launch_bounds__(256) void k_adjacency(
    const float* __restrict__ neg, const float* __restrict__ neu,
    unsigned short* __restrict__ Sghi, unsigned short* __restrict__ Sglo,
    unsigned short* __restrict__ Suhi, unsigned short* __restrict__ Sulo)
{
  const float* ne = blockIdx.y ? neu : neg;
  unsigned short* Shi = blockIdx.y ? Suhi : Sghi;
  unsigned short* Slo = blockIdx.y ? Sulo : Sglo;
  int n = blockIdx.x;
  int tid = threadIdx.x;
  const f32x4v* rp = (const f32x4v*)(ne + n*DDIM);
  f32x4v r0 = rp[0], r1 = rp[1], r2 = rp[2], r3 = rp[3];
  float v[4]; float mx = -3.4e38f;
#pragma unroll
  for (int j = 0; j < 4; ++j) {
    int m = tid + j*256;
    const f32x4v* p = (const f32x4v*)(ne + m*DDIM);
    f32x4v q0 = p[0], q1 = p[1], q2 = p[2], q3 = p[3];
    float dot = r0[0]*q0[0] + r0[1]*q0[1] + r0[2]*q0[2] + r0[3]*q0[3]
              + r1[0]*q1[0] + r1[1]*q1[1] + r1[2]*q1[2] + r1[3]*q1[3]
              + r2[0]*q2[0] + r2[1]*q2[1] + r2[2]*q2[2] + r2[3]*q2[3]
              + r3[0]*q3[0] + r3[1]*q3[1] + r3[2]*q3[2] + r3[3]*q3[3];
    v[j] = dot; mx = fmaxf(mx, dot);
  }
  __shared__ float red[256];
  red[tid] = mx; __syncthreads();
#pragma unroll
  for (int s = 128; s > 0; s >>= 1) {
    if (tid < s) red[tid] = fmaxf(red[tid], red[tid+s]);
    __syncthreads();
  }
  mx = red[0]; __syncthreads();
  float sum = 0.f;
#pragma unroll
  for (int j = 0; j < 4; ++j) { v[j] = expf(v[j] - mx); sum += v[j]; }
  red[tid] = sum; __syncthreads();
#pragma unroll
  for (int s = 128; s > 0; s >>= 1) {
    if (tid < s) red[tid] += red[tid+s];
    __syncthreads();
  }
  float inv = 1.0f / red[0];
#pragma unroll
  for (int j = 0; j < 4; ++j) {
    float s = v[j]*inv;
    unsigned short hi = f2bf(s);
    Shi[n*NNODE + tid + j*256] = hi;
    Slo[n*NNODE + tid + j*256] = f2bf(s - bf2f(hi));
  }
}

// ---------------- pack X[m][b*65+c] as hi/lo bf16 split ----------------
__global__ __launch_bounds__(256) void k_pack(
    const float* __restrict__ xt,    // x + t*NNODE ; element b*(T*N) + m
    const float* __restrict__ state, // [N][B][H]
    unsigned short* __restrict__ Xhi, unsigned short* __restrict__ Xlo)
{
  int m = blockIdx.x;
  for (int idx = threadIdx.x; idx < LDB; idx += 256) {
    float v = 0.f;
    if (idx < BC) {
      int b = idx / CCH, c = idx - b*CCH;
      v = (c == 0) ? xt[b*(T_STEPS*NNODE) + m] : state[(m*BBATCH + b)*HHID + (c-1)];
    }
    unsigned short hi = f2bf(v);
    Xhi[(size_t)m*LDB + idx] = hi;
    Xlo[(size_t)m*LDB + idx] = f2bf(v - bf2f(hi));
  }
}

// ------- per-node weight bank (fp32): Wn[nl][j] = sum_d ne[n][d]*src[d][j] ----
__global__ __launch_bounds__(256) void k_wn(
    const float* __restrict__ ne,    // [1024][16]
    const float* __restrict__ W,     // [16][JW]
    const float* __restrict__ bias,  // [16][OB]
    float* __restrict__ Wn,          // [NCHUNK][J] fp32
    int nbase, int JW, int OB, int J)
{
  int tid = threadIdx.x;
  int j = blockIdx.x * 256 + tid;
  int nl0 = blockIdx.y * 128;
  int n0 = nbase + nl0;
  __shared__ float nes[128*DDIM];
  for (int e = tid; e < 128*DDIM; e += 256) nes[e] = ne[n0*DDIM + e];
  float w[DDIM];
  bool isW = (j < JW);
#pragma unroll
  for (int d = 0; d < DDIM; ++d)
    w[d] = isW ? W[d*JW + j] : bias[d*OB + (j - JW)];
  __syncthreads();
  for (int nn = 0; nn < 128; ++nn) {
    float a = 0.f;
#pragma unroll
    for (int d = 0; d < DDIM; ++d) a += w[d] * nes[nn*DDIM + d];
    Wn[(size_t)(nl0 + nn)*J + j] = a;
  }
}

// ---- 3-term split bf16 MFMA GEMM: C = Ahi*Bhi + Ahi*Blo + Alo*Bhi (fp32 acc)
// C[1024][LDB] = A[1024][1024]*B[1024][LDB]; 64x128 tile, BK=32, 2x2 waves
template<int WRITE_SPLIT>
__global__ __launch_bounds__(256) void k_gemm3(
    const unsigned short* __restrict__ Ahi, const unsigned short* __restrict__ Alo,
    const unsigned short* __restrict__ Bhi, const unsigned short* __restrict__ Blo,
    float* __restrict__ Cf,
    unsigned short* __restrict__ Chi, unsigned short* __restrict__ Clo)
{
  __shared__ unsigned short As[2][64][40];
  __shared__ unsigned short Bs[2][128][40];   // [plane][col][k swizzled]
  int n0 = blockIdx.x * 128;
  int m0 = blockIdx.y * 64;
  int tid = threadIdx.x;
  int lane = tid & 63, wave = tid >> 6;
  int wr = wave >> 1, wc = wave & 1;
  int lr = lane & 15, lq = lane >> 4;
  int arow = tid >> 2, ac8 = (tid & 3) * 8;         // A staging: 64 rows x 32 k
  int bkp = tid >> 4, bc0 = (tid & 15) * 8;         // B staging: k-pair, 8 cols
  int kIx[8];
#pragma unroll
  for (int j = 0; j < 8; ++j)
    kIx[j] = (2*bkp) ^ ((((bc0 + j) >> 3) & 3) << 3);

  f32x4v acc[2][4];
#pragma unroll
  for (int f = 0; f < 2; ++f)
#pragma unroll
    for (int g = 0; g < 4; ++g) acc[f][g] = (f32x4v){0.f,0.f,0.f,0.f};

  for (int k0 = 0; k0 < NNODE; k0 += 32) {
    // stage A hi/lo (linear)
    *(ush8*)&As[0][arow][ac8] = *(const ush8*)&Ahi[(size_t)(m0+arow)*NNODE + k0 + ac8];
    *(ush8*)&As[1][arow][ac8] = *(const ush8*)&Alo[(size_t)(m0+arow)*NNODE + k0 + ac8];
    // stage B hi: transpose + octet swizzle  Bs[p][col][k ^ (8*((col>>3)&3))]
    {
      ush8 b0 = *(const ush8*)&Bhi[(size_t)(k0 + 2*bkp    )*LDB + n0 + bc0];
      ush8 b1 = *(const ush8*)&Bhi[(size_t)(k0 + 2*bkp + 1)*LDB + n0 + bc0];
#pragma unroll
      for (int j = 0; j < 8; ++j)
        *(unsigned int*)&Bs[0][bc0+j][kIx[j]] =
            (unsigned)b0[j] | ((unsigned)b1[j] << 16);
    }
    // stage B lo
    {
      ush8 b0 = *(const ush8*)&Blo[(size_t)(k0 + 2*bkp    )*LDB + n0 + bc0];
      ush8 b1 = *(const ush8*)&Blo[(size_t)(k0 + 2*bkp + 1)*LDB + n0 + bc0];
#pragma unroll
      for (int j = 0; j < 8; ++j)
        *(unsigned int*)&Bs[1][bc0+j][kIx[j]] =
            (unsigned)b0[j] | ((unsigned)b1[j] << 16);
    }
    __syncthreads();
    short8 ah[2], al[2], bh[4], bl[4];
#pragma unroll
    for (int f = 0; f < 2; ++f) {
      ah[f] = *(const short8*)&As[0][wr*32 + f*16 + lr][lq*8];
      al[f] = *(const short8*)&As[1][wr*32 + f*16 + lr][lq*8];
    }
#pragma unroll
    for (int g = 0; g < 4; ++g) {
      int col = wc*64 + g*16 + lr;
      int oct = lq ^ ((col >> 3) & 3);
      bh[g] = *(const short8*)&Bs[0][col][oct*8];
      bl[g] = *(const short8*)&Bs[1][col][oct*8];
    }
#pragma unroll
    for (int f = 0; f < 2; ++f)
#pragma unroll
      for (int g = 0; g < 4; ++g) {
        acc[f][g] = __builtin_amdgcn_mfma_f32_16x16x32_bf16(ah[f], bh[g], acc[f][g], 0, 0, 0);
        acc[f][g] = __builtin_amdgcn_mfma_f32_16x16x32_bf16(ah[f], bl[g], acc[f][g], 0, 0, 0);
        acc[f][g] = __builtin_amdgcn_mfma_f32_16x16x32_bf16(al[f], bh[g], acc[f][g], 0, 0, 0);
      }
    __syncthreads();
  }
  // epilogue: row = m0+wr*32+f*16+lq*4+r, col = n0+wc*64+g*16+lr
#pragma unroll
  for (int f = 0; f < 2; ++f) {
#pragma unroll
    for (int g = 0; g < 4; ++g) {
      int col = n0 + wc*64 + g*16 + lr;
#pragma unroll
      for (int r = 0; r < 4; ++r) {
        int row = m0 + wr*32 + f*16 + lq*4 + r;
        float v = acc[f][g][r];
        if (WRITE_SPLIT) {
          unsigned short hi = f2bf(v);
          Chi[(size_t)row*LDB + col] = hi;
          Clo[(size_t)row*LDB + col] = f2bf(v - bf2f(hi));
        } else {
          Cf[(size_t)row*LDB + col] = v;
        }
      }
    }
  }
}

// ------- gate GCN out (fp32): sigmoid; z*state -> Xhi/Xlo cols, r -> rbuf ----
__global__ __launch_bounds__(256) void k_gate_out(
    unsigned short* __restrict__ Xhi, unsigned short* __restrict__ Xlo,
    const unsigned short* __restrict__ Y1hi, const unsigned short* __restrict__ Y1lo,
    const float* __restrict__ Y2,
    const float* __restrict__ Wn,     // [NCHUNK][196*128] fp32
    const float* __restrict__ state, float* __restrict__ rbuf, int nbase)
{
  int n = nbase + blockIdx.x, tid = threadIdx.x;
  __shared__ float xs[64 * XS_STRIDE];   // 50.4 KB
  __shared__ float wsh[14 * 132];        // 7.4 KB
  size_t rowb = (size_t)n * LDB;
  for (int idx = tid; idx < BC; idx += 256) {
    int b = idx / CCH, c = idx - b*CCH;
    float x0 = bf2f(Xhi[rowb + idx]) + bf2f(Xlo[rowb + idx]);
    float a1 = bf2f(Y1hi[rowb + idx]) + bf2f(Y1lo[rowb + idx]);
    float a2 = Y2[rowb + idx];
    float* xb = xs + b*XS_STRIDE;
    xb[c] = x0; xb[65+c] = a1; xb[130+c] = 2.f*a2 - x0;
  }
  if (tid < 64) xs[tid*XS_STRIDE + 195] = 1.0f;
  int bs = tid >> 4, os = tid & 15;
  float acc[4][8];
#pragma unroll
  for (int i = 0; i < 4; ++i)
#pragma unroll
    for (int j = 0; j < 8; ++j) acc[i][j] = 0.f;
  const float* Wnn = Wn + (size_t)(n - nbase) * (KI*128);
  for (int ch = 0; ch < 14; ++ch) {
    __syncthreads();
    for (int e = tid; e < 448; e += 256) {
      int ki = e >> 5, q = e & 31;
      *(f32x4v*)&wsh[ki*132 + q*4] = *(const f32x4v*)&Wnn[(ch*14 + ki)*128 + q*4];
    }
    __syncthreads();
#pragma unroll 2
    for (int kk = 0; kk < 14; ++kk) {
      int ki = ch*14 + kk;
      float a0 = xs[(bs*4+0)*XS_STRIDE + ki];
      float a1 = xs[(bs*4+1)*XS_STRIDE + ki];
      float a2 = xs[(bs*4+2)*XS_STRIDE + ki];
      float a3 = xs[(bs*4+3)*XS_STRIDE + ki];
#pragma unroll
      for (int q = 0; q < 4; ++q) {
        f32x2v w = *(const f32x2v*)&wsh[kk*132 + os*2 + q*32];
        acc[0][2*q]   += a0*w[0]; acc[0][2*q+1] += a0*w[1];
        acc[1][2*q]   += a1*w[0]; acc[1][2*q+1] += a1*w[1];
        acc[2][2*q]   += a2*w[0]; acc[2][2*q+1] += a2*w[1];
        acc[3][2*q]   += a3*w[0]; acc[3][2*q+1] += a3*w[1];
      }
    }
  }
#pragma unroll
  for (int bb = 0; bb < 4; ++bb) {
    int b = bs*4 + bb;
#pragma unroll
    for (int jj = 0; jj < 8; ++jj) {
      int o = os*2 + (jj>>1)*32 + (jj&1);
      float s = 1.f / (1.f + expf(-acc[bb][jj]));
      if (jj < 4) {   // o < 64 -> z; write z*state into candidate cols
        int si = n*4096 + b*64 + o;
        float zs = s * state[si];
        size_t cix = rowb + b*CCH + 1 + o;
        unsigned short hi = f2bf(zs);
        Xhi[cix] = hi;
        Xlo[cix] = f2bf(zs - bf2f(hi));
      } else {        // r
        rbuf[n*4096 + b*64 + (o - 64)] = s;
      }
    }
  }
}

// ------- update GCN out (fp32): tanh; h = r*st + (1-r)*hc -------------------
__global__ __launch_bounds__(256) void k_update_out(
    const unsigned short* __restrict__ Xhi, const unsigned short* __restrict__ Xlo,
    const unsigned short* __restrict__ Y1hi, const unsigned short* __restrict__ Y1lo,
    const float* __restrict__ Y2,
    const float* __restrict__ Wn,     // [NCHUNK][196*64] fp32
    const float* __restrict__ rbuf, float* __restrict__ state,
    float* __restrict__ outT, int nbase)
{
  int n = nbase + blockIdx.x, tid = threadIdx.x;
  __shared__ float xs[64 * XS_STRIDE];
  __shared__ float wsh[14 * 68];
  size_t rowb = (size_t)n * LDB;
  for (int idx = tid; idx < BC; idx += 256) {
    int b = idx / CCH, c = idx - b*CCH;
    float x0 = bf2f(Xhi[rowb + idx]) + bf2f(Xlo[rowb + idx]);
    float a1 = bf2f(Y1hi[rowb + idx]) + bf2f(Y1lo[rowb + idx]);
    float a2 = Y2[rowb + idx];
    float* xb = xs + b*XS_STRIDE;
    xb[c] = x0; xb[65+c] = a1; xb[130+c] = 2.f*a2 - x0;
  }
  if (tid < 64) xs[tid*XS_STRIDE + 195] = 1.0f;
  int bs = tid >> 4, os = tid & 15;
  float acc[4][4];
#pragma unroll
  for (int i = 0; i < 4; ++i)
#pragma unroll
    for (int j = 0; j < 4; ++j) acc[i][j] = 0.f;
  const float* Wnn = Wn + (size_t)(n - nbase) * (KI*64);
  for (int ch = 0; ch < 14; ++ch) {
    __syncthreads();
    for (int e = tid; e < 224; e += 256) {
      int ki = e >> 4, q = e & 15;
      *(f32x4v*)&wsh[ki*68 + q*4] = *(const f32x4v*)&Wnn[(ch*14 + ki)*64 + q*4];
    }
    __syncthreads();
#pragma unroll 2
    for (int kk = 0; kk < 14; ++kk) {
      int ki = ch*14 + kk;
      float a0 = xs[(bs*4+0)*XS_STRIDE + ki];
      float a1 = xs[(bs*4+1)*XS_STRIDE + ki];
      float a2 = xs[(bs*4+2)*XS_STRIDE + ki];
      float a3 = xs[(bs*4+3)*XS_STRIDE + ki];
#pragma unroll
      for (int q = 0; q < 2; ++q) {
        f32x2v w = *(const f32x2v*)&wsh[kk*68 + os*2 + q*32];
        acc[0][2*q]   += a0*w[0]; acc[0][2*q+1] += a0*w[1];
        acc[1][2*q]   += a1*w[0]; acc[1][2*q+1] += a1*w[1];
        acc[2][2*q]   += a2*w[0]; acc[2][2*q+1] += a2*w[1];
        acc[3][2*q]   += a3*w[0]; acc[3][2*q+1] += a3*w[1];
      }
    }
  }
#pragma unroll
  for (int bb = 0; bb < 4; ++bb) {
    int b = bs*4 + bb;
#pragma unroll
    for (int jj = 0; jj < 4; ++jj) {
      int o = os*2 + (jj>>1)*32 + (jj&1);
      float hc = tanhf(acc[bb][jj]);
      int si = n*4096 + b*64 + o;
      float r = rbuf[si];
      float st = state[si];
      float h = r*st + (1.0f - r)*hc;
      state[si] = h;
      outT[(size_t)b*(T_STEPS*NNODE*HHID) + n*HHID + o] = h;
    }
  }
}

extern "C" void kernel_launch(void* const* d_in, const int* in_sizes, int n_in,
                              void* d_out, int out_size, void* d_ws, size_t ws_size,
                              hipStream_t stream) {
  const float* x          = (const float*)d_in[0];
  const float* node_emb   = (const float*)d_in[1];
  const float* time_emb   = (const float*)d_in[2];
  const float* gate_W     = (const float*)d_in[3];   // [16][3][65][128]
  const float* gate_b     = (const float*)d_in[4];   // [16][128]
  const float* gate_ln_g  = (const float*)d_in[5];
  const float* gate_ln_b  = (const float*)d_in[6];
  const float* update_W   = (const float*)d_in[7];   // [16][3][65][64]
  const float* update_b   = (const float*)d_in[8];   // [16][64]
  const float* update_ln_g= (const float*)d_in[9];
  const float* update_ln_b= (const float*)d_in[10];
  float* out = (float*)d_out;
  char* ws = (char*)d_ws;

  // workspace layout (bytes); total 119,668,736 (~114.1 MiB)
  float*          neg   = (float*)(ws + 0);
  float*          neu   = (float*)(ws + 65536);
  unsigned short* Sghi  = (unsigned short*)(ws + 131072);
  unsigned short* Sglo  = (unsigned short*)(ws + 2228224);
  unsigned short* Suhi  = (unsigned short*)(ws + 4325376);
  unsigned short* Sulo  = (unsigned short*)(ws + 6422528);
  unsigned short* Xhi   = (unsigned short*)(ws + 8519680);
  unsigned short* Xlo   = (unsigned short*)(ws + 17170432);
  unsigned short* Y1hi  = (unsigned short*)(ws + 25821184);
  unsigned short* Y1lo  = (unsigned short*)(ws + 34471936);
  float*          Y2    = (float*)(ws + 43122688);
  float*          state = (float*)(ws + 60424192);
  float*          rbuf  = (float*)(ws + 77201408);
  float*          Wn    = (float*)(ws + 93978624);   // 25.7 MB chunk

  (void)hipMemsetAsync(state, 0, (size_t)NNODE*BBATCH*HHID*sizeof(float), stream);

  for (int t = 0; t < T_STEPS; ++t) {
    k_embed_ln<<<dim3(4), 256, 0, stream>>>(node_emb, time_emb + t*DDIM,
        gate_ln_g, gate_ln_b, update_ln_g, update_ln_b, neg, neu);
    k_adjacency<<<dim3(NNODE, 2), 256, 0, stream>>>(neg, neu, Sghi, Sglo, Suhi, Sulo);
    k_pack<<<dim3(NNODE), 256, 0, stream>>>(x + t*NNODE, state, Xhi, Xlo);
    // ---- gate phase ----
    k_gemm3<1><<<dim3(33, 16), 256, 0, stream>>>(Sghi, Sglo, Xhi,  Xlo,
        (float*)nullptr, Y1hi, Y1lo);
    k_gemm3<0><<<dim3(33, 16), 256, 0, stream>>>(Sghi, Sglo, Y1hi, Y1lo,
        Y2, (unsigned short*)nullptr, (unsigned short*)nullptr);
    for (int q = 0; q < 4; ++q) {
      k_wn<<<dim3(98, 2), 256, 0, stream>>>(neg, gate_W, gate_b, Wn,
          q*NCHUNK, 24960, 128, 25088);
      k_gate_out<<<dim3(NCHUNK), 256, 0, stream>>>(Xhi, Xlo, Y1hi, Y1lo, Y2,
          Wn, state, rbuf, q*NCHUNK);
    }
    // ---- update phase (candidate now in Xhi/Xlo) ----
    k_gemm3<1><<<dim3(33, 16), 256, 0, stream>>>(Suhi, Sulo, Xhi,  Xlo,
        (float*)nullptr, Y1hi, Y1lo);
    k_gemm3<0><<<dim3(33, 16), 256, 0, stream>>>(Suhi, Sulo, Y1hi, Y1lo,
        Y2, (unsigned short*)nullptr, (unsigned short*)nullptr);
    for (int q = 0; q < 4; ++q) {
      k_wn<<<dim3(49, 2), 256, 0, stream>>>(neu, update_W, update_b, Wn,
          q*NCHUNK, 12480, 64, 12544);
      k_update_out<<<dim3(NCHUNK), 256, 0, stream>>>(Xhi, Xlo, Y1hi, Y1lo, Y2,
          Wn, rbuf, state, out + (size_t)t*NNODE*HHID, q*NCHUNK);
    }
  }
}